// Round 11
// baseline (108.831 us; speedup 1.0000x reference)
//
#include <hip/hip_runtime.h>
#include <cstdint>

#define CD 64
#define HWD 589824
#define K1_GRID 1152
#define T_PER 4                       // tiles (128 cols) per block
#define K1_ROWS (K1_GRID * T_PER)     // 4608 cell rows
#define FMAXV 3.402823466e+38f

#define AS1 __attribute__((address_space(1)))
#define AS3 __attribute__((address_space(3)))

typedef float f32x16 __attribute__((ext_vector_type(16)));
typedef short bf16x8 __attribute__((ext_vector_type(8)));

__device__ __forceinline__ short f2bf(float f) {
    unsigned u = __float_as_uint(f);
    u = u + 0x7FFFu + ((u >> 16) & 1u);   // RNE
    return (short)(u >> 16);
}

// sorted top-4 insert: t.x <= t.y <= t.z <= t.w
__device__ __forceinline__ void ins4(float4& t, float x) {
    if (x < t.w) {
        if (x < t.z) { t.w = t.z;
            if (x < t.y) { t.z = t.y;
                if (x < t.x) { t.y = t.x; t.x = x; } else t.y = x;
            } else t.z = x;
        } else t.w = x;
    }
}

// kA: 64 blocks x 64 thr; thread k of block p loads one sel element.
// Also resets the completion ticket for this launch.
__global__ __launch_bounds__(64) void kA_pack(
    const float* __restrict__ f1, const int* __restrict__ nidx,
    short* __restrict__ sel_bf, float* __restrict__ sel2,
    unsigned* __restrict__ ticket)
{
    const int p = blockIdx.x, k = threadIdx.x;
    if (p == 0 && k == 0) *ticket = 0u;
    float v = f1[(long)k * HWD + nidx[p]];
    float s = v * v;
#pragma unroll
    for (int off = 32; off; off >>= 1) s += __shfl_xor(s, off);
    sel_bf[p * CD + k] = f2bf(v);
    if (k == 0) sel2[p] = s;
}

// k1: 1152 blocks (2/CU), 4 tiles each, double-buffered LDS + counted vmcnt
// pipeline (stage t+1 stays in flight across the barrier while computing t).
__global__ __launch_bounds__(256, 2) void k1_topk(
    const float* __restrict__ f2, const short* __restrict__ sel_bf,
    const float* __restrict__ sel2, float4* __restrict__ cells)
{
    __shared__ float lds[2][CD][128];   // 64 KB
    __shared__ float4 lm[4][CD];        // 4 KB
    const int tid = threadIdx.x;
    const int lane = tid & 63, wid = tid >> 6;
    const int l31 = lane & 31, lh = lane >> 5;
    const long nb = (long)blockIdx.x * (T_PER * 128);

#define STAGE(buf, ncol0) do {                                              \
        const int srow2_ = lane >> 5;                                       \
        const int scol_  = (lane & 31) * 4;                                 \
        _Pragma("unroll")                                                   \
        for (int kk = 0; kk < 8; ++kk) {                                    \
            int k_ = wid * 16 + kk * 2;                                     \
            const float* gp_ = f2 + (long)(k_ + srow2_) * HWD + (ncol0) + scol_; \
            __builtin_amdgcn_global_load_lds((const AS1 void*)gp_,          \
                                             (AS3 void*)&lds[buf][k_][0], 16, 0, 0); \
        }                                                                   \
    } while (0)

    // sel fragments + norms FIRST (so compiler's wait for them is vmcnt(8)
    // in the prologue, not a vmcnt(0) inside the loop)
    bf16x8 sf0[4], sf1[4];
#pragma unroll
    for (int ks = 0; ks < 4; ++ks) {
        sf0[ks] = *(const bf16x8*)(sel_bf + l31 * CD + 16 * ks + 8 * lh);
        sf1[ks] = *(const bf16x8*)(sel_bf + (l31 + 32) * CD + 16 * ks + 8 * lh);
    }
    const float sel20 = sel2[l31], sel21 = sel2[l31 + 32];
    __builtin_amdgcn_sched_barrier(0);

    STAGE(0, nb);                       // tile 0 -> buf 0
    __builtin_amdgcn_sched_barrier(0);

#pragma unroll
    for (int t = 0; t < T_PER; ++t) {
        if (t + 1 < T_PER) {
            STAGE((t + 1) & 1, nb + (long)(t + 1) * 128);
            __builtin_amdgcn_sched_barrier(0);
            asm volatile("s_waitcnt vmcnt(8)" ::: "memory");   // tile t done; t+1 in flight
        } else {
            asm volatile("s_waitcnt vmcnt(0)" ::: "memory");
        }
        __builtin_amdgcn_sched_barrier(0);
        __builtin_amdgcn_s_barrier();   // raw: no compiler vmcnt(0) drain
        __builtin_amdgcn_sched_barrier(0);

        const int col = wid * 32 + l31;
        float fs = 0.f;
        f32x16 a0, a1;
#pragma unroll
        for (int i = 0; i < 16; ++i) { a0[i] = 0.f; a1[i] = 0.f; }
#pragma unroll
        for (int ks = 0; ks < 4; ++ks) {
            bf16x8 af;
#pragma unroll
            for (int j = 0; j < 8; ++j) {
                float v = lds[t & 1][16 * ks + 8 * lh + j][col];
                fs += v * v;
                af[j] = f2bf(v);
            }
            a0 = __builtin_amdgcn_mfma_f32_32x32x16_bf16(af, sf0[ks], a0, 0, 0, 0);
            a1 = __builtin_amdgcn_mfma_f32_32x32x16_bf16(af, sf1[ks], a1, 0, 0, 0);
        }
        fs += __shfl_xor(fs, 32);       // combine k-halves (same col)

        float4 tt = make_float4(FMAXV, FMAXV, FMAXV, FMAXV);
        float4 uu = tt;
#pragma unroll
        for (int i = 0; i < 16; ++i) {
            int r = (i & 3) + 8 * (i >> 2) + 4 * lh;
            float fr2 = __shfl(fs, r);
            ins4(tt, fmaxf(sel20 + fr2 - 2.f * a0[i], 0.f));   // p = l31
            ins4(uu, fmaxf(sel21 + fr2 - 2.f * a1[i], 0.f));   // p = l31+32
        }
        // merge the two lh halves (lanes l and l^32 hold the same p)
        {
            float4 o;
            o.x = __shfl_xor(tt.x, 32); o.y = __shfl_xor(tt.y, 32);
            o.z = __shfl_xor(tt.z, 32); o.w = __shfl_xor(tt.w, 32);
            ins4(tt, o.x); ins4(tt, o.y); ins4(tt, o.z); ins4(tt, o.w);
            o.x = __shfl_xor(uu.x, 32); o.y = __shfl_xor(uu.y, 32);
            o.z = __shfl_xor(uu.z, 32); o.w = __shfl_xor(uu.w, 32);
            ins4(uu, o.x); ins4(uu, o.y); ins4(uu, o.z); ins4(uu, o.w);
        }
        if (lh == 0) { lm[wid][l31] = tt; lm[wid][l31 + 32] = uu; }
        asm volatile("s_waitcnt lgkmcnt(0)" ::: "memory");  // tile reads + lm writes drained
        __builtin_amdgcn_sched_barrier(0);
        __builtin_amdgcn_s_barrier();   // after this: buf[t&1] free for restage
        __builtin_amdgcn_sched_barrier(0);

        if (wid == (t & 3)) {           // rotate merge wave
            float4 m  = lm[0][lane];
            float4 b1 = lm[1][lane], b2 = lm[2][lane], b3 = lm[3][lane];
            ins4(m, b1.x); ins4(m, b1.y); ins4(m, b1.z); ins4(m, b1.w);
            ins4(m, b2.x); ins4(m, b2.y); ins4(m, b2.z); ins4(m, b2.w);
            ins4(m, b3.x); ins4(m, b3.y); ins4(m, b3.z); ins4(m, b3.w);
            cells[(long)(blockIdx.x * T_PER + t) * CD + lane] = m;
        }
    }
#undef STAGE
}

// k2: 64 blocks x 1024 thr; block p: per-thread sorted top-4 over its rows
// of cells[.][p], then 16 rounds of block-wide min extraction. Last finished
// block (ticket) does the deterministic ordered final sum.
__global__ __launch_bounds__(1024) void k2_sel(
    const float4* __restrict__ cells, float* __restrict__ partial,
    unsigned* __restrict__ ticket, float* __restrict__ out)
{
    const int p = blockIdx.x;
    const int tid = threadIdx.x;
    const int lane = tid & 63, wid = tid >> 6;
    __shared__ unsigned long long wmin[16];

    float4 b0 = cells[(long)(tid)        * CD + p];
    float4 b1 = cells[(long)(tid + 1024) * CD + p];
    float4 b2 = cells[(long)(tid + 2048) * CD + p];
    float4 b3 = cells[(long)(tid + 3072) * CD + p];
    float4 b4 = (tid < K1_ROWS - 4096)
                ? cells[(long)(tid + 4096) * CD + p]
                : make_float4(FMAXV, FMAXV, FMAXV, FMAXV);

    float4 t = make_float4(FMAXV, FMAXV, FMAXV, FMAXV);
    ins4(t, b0.x); ins4(t, b0.y); ins4(t, b0.z); ins4(t, b0.w);
    ins4(t, b1.x); ins4(t, b1.y); ins4(t, b1.z); ins4(t, b1.w);
    ins4(t, b2.x); ins4(t, b2.y); ins4(t, b2.z); ins4(t, b2.w);
    ins4(t, b3.x); ins4(t, b3.y); ins4(t, b3.z); ins4(t, b3.w);
    ins4(t, b4.x); ins4(t, b4.y); ins4(t, b4.z); ins4(t, b4.w);

    float sum = 0.f;
    for (int rd = 0; rd < 16; ++rd) {
        unsigned long long key =
            ((unsigned long long)__float_as_uint(t.x) << 32) | (unsigned)tid;
#pragma unroll
        for (int off = 32; off; off >>= 1) {
            unsigned long long o = __shfl_xor(key, off);
            if (o < key) key = o;
        }
        if (lane == 0) wmin[wid] = key;
        __syncthreads();
        unsigned long long gk = wmin[0];
#pragma unroll
        for (int w = 1; w < 16; ++w) if (wmin[w] < gk) gk = wmin[w];
        sum += __uint_as_float((unsigned)(gk >> 32));
        if ((unsigned)(gk & 0xFFFFFFFFu) == (unsigned)tid) {
            t.x = t.y; t.y = t.z; t.z = t.w; t.w = FMAXV;   // pop local min
        }
        __syncthreads();
    }

    if (tid == 0) {
        partial[p] = sum;
        __threadfence();
        unsigned tk = atomicAdd(ticket, 1u);
        if (tk == CD - 1) {          // last block: deterministic ordered sum
            __threadfence();
            float s = 0.f;
            const volatile float* vp = partial;
            for (int q = 0; q < CD; ++q) s += vp[q];
            out[0] = -s / 1024.0f;
        }
    }
}

extern "C" void kernel_launch(void* const* d_in, const int* in_sizes, int n_in,
                              void* d_out, int out_size, void* d_ws, size_t ws_size,
                              hipStream_t stream)
{
    const float* f1   = (const float*)d_in[0];
    const float* f2   = (const float*)d_in[1];
    const int*   nidx = (const int*)d_in[3];     // negative_indices
    float* out = (float*)d_out;

    float4*   cells   = (float4*)d_ws;                          // 4608*64*16 = 4.7 MB
    short*    sel_bf  = (short*)(cells + (long)K1_ROWS * CD);   // 8 KB
    float*    sel2    = (float*)(sel_bf + CD * CD);
    float*    partial = sel2 + CD;
    unsigned* ticket  = (unsigned*)(partial + CD);

    kA_pack<<<CD,        64, 0, stream>>>(f1, nidx, sel_bf, sel2, ticket);
    k1_topk<<<K1_GRID,  256, 0, stream>>>(f2, sel_bf, sel2, cells);
    k2_sel <<<CD,      1024, 0, stream>>>(cells, partial, ticket, out);
}

// Round 12
// 84.175 us; speedup vs baseline: 1.2929x; 1.2929x over previous
//
#include <hip/hip_runtime.h>
#include <cstdint>

#define CD 64
#define HWD 589824
#define K1_GRID 1152
#define T_PER 4                       // 32-col tiles per wave
#define K1_ROWS (K1_GRID * 4)         // 4608 cell rows (one per wave)
#define FMAXV 3.402823466e+38f

#define AS1 __attribute__((address_space(1)))
#define AS3 __attribute__((address_space(3)))

typedef float f32x16 __attribute__((ext_vector_type(16)));
typedef short bf16x8 __attribute__((ext_vector_type(8)));

__device__ __forceinline__ short f2bf(float f) {
    unsigned u = __float_as_uint(f);
    u = u + 0x7FFFu + ((u >> 16) & 1u);   // RNE
    return (short)(u >> 16);
}

// sorted top-4 insert: t.x <= t.y <= t.z <= t.w
__device__ __forceinline__ void ins4(float4& t, float x) {
    if (x < t.w) {
        if (x < t.z) { t.w = t.z;
            if (x < t.y) { t.z = t.y;
                if (x < t.x) { t.y = t.x; t.x = x; } else t.y = x;
            } else t.z = x;
        } else t.w = x;
    }
}

// kA: 64 blocks x 64 thr; thread k of block p loads one sel element.
// Also resets the completion ticket for this launch.
__global__ __launch_bounds__(64) void kA_pack(
    const float* __restrict__ f1, const int* __restrict__ nidx,
    short* __restrict__ sel_bf, float* __restrict__ sel2,
    unsigned* __restrict__ ticket)
{
    const int p = blockIdx.x, k = threadIdx.x;
    if (p == 0 && k == 0) *ticket = 0u;
    float v = f1[(long)k * HWD + nidx[p]];
    float s = v * v;
#pragma unroll
    for (int off = 32; off; off >>= 1) s += __shfl_xor(s, off);
    sel_bf[p * CD + k] = f2bf(v);
    if (k == 0) sel2[p] = s;
}

// k1: wave-private, barrier-free. Each wave owns an 8KB LDS slice [64][32]
// and 4 contiguous 32-col tiles: stage via global_load_lds -> vmcnt(0) (own
// loads only) -> MFMA distances -> running sorted top-4 per p across tiles.
// 32KB LDS/block -> 4 blocks/CU, 16 fully independent waves/CU.
__global__ __launch_bounds__(256, 4) void k1_topk(
    const float* __restrict__ f2, const short* __restrict__ sel_bf,
    const float* __restrict__ sel2, float4* __restrict__ cells)
{
    __shared__ float lds[4][CD][32];   // 32 KB, one slice per wave
    const int tid = threadIdx.x;
    const int lane = tid & 63, wid = tid >> 6;
    const int l31 = lane & 31, lh = lane >> 5;
    const int gw = blockIdx.x * 4 + wid;          // 0..4607
    const long nb = (long)gw * (T_PER * 32);

    bf16x8 sf0[4], sf1[4];
#pragma unroll
    for (int ks = 0; ks < 4; ++ks) {
        sf0[ks] = *(const bf16x8*)(sel_bf + l31 * CD + 16 * ks + 8 * lh);
        sf1[ks] = *(const bf16x8*)(sel_bf + (l31 + 32) * CD + 16 * ks + 8 * lh);
    }
    const float sel20 = sel2[l31], sel21 = sel2[l31 + 32];

    const int srow = lane >> 3;        // 0..7
    const int scol = (lane & 7) * 4;   // 0,4,..,28

    float4 t = make_float4(FMAXV, FMAXV, FMAXV, FMAXV);
    float4 u = t;

#pragma unroll
    for (int tt = 0; tt < T_PER; ++tt) {
        const long n0 = nb + (long)tt * 32;

        // stage own slice: 8 x 1KB (8 rows each), linear LDS dest
#pragma unroll
        for (int kk = 0; kk < 8; ++kk) {
            const float* gp = f2 + (long)(8 * kk + srow) * HWD + n0 + scol;
            __builtin_amdgcn_global_load_lds((const AS1 void*)gp,
                                             (AS3 void*)&lds[wid][8 * kk][0], 16, 0, 0);
        }
        asm volatile("s_waitcnt vmcnt(0)" ::: "memory");   // own loads only
        __builtin_amdgcn_sched_barrier(0);

        float fs = 0.f;
        f32x16 a0, a1;
#pragma unroll
        for (int i = 0; i < 16; ++i) { a0[i] = 0.f; a1[i] = 0.f; }
#pragma unroll
        for (int ks = 0; ks < 4; ++ks) {
            bf16x8 af;
#pragma unroll
            for (int j = 0; j < 8; ++j) {
                float v = lds[wid][16 * ks + 8 * lh + j][l31];
                fs += v * v;
                af[j] = f2bf(v);
            }
            a0 = __builtin_amdgcn_mfma_f32_32x32x16_bf16(af, sf0[ks], a0, 0, 0, 0);
            a1 = __builtin_amdgcn_mfma_f32_32x32x16_bf16(af, sf1[ks], a1, 0, 0, 0);
        }
        fs += __shfl_xor(fs, 32);      // combine k-halves (same col)

#pragma unroll
        for (int i = 0; i < 16; ++i) {
            int r = (i & 3) + 8 * (i >> 2) + 4 * lh;
            float fr2 = __shfl(fs, r);
            ins4(t, fmaxf(sel20 + fr2 - 2.f * a0[i], 0.f));   // p = l31
            ins4(u, fmaxf(sel21 + fr2 - 2.f * a1[i], 0.f));   // p = l31+32
        }
        asm volatile("s_waitcnt lgkmcnt(0)" ::: "memory");    // slice reads done
        __builtin_amdgcn_sched_barrier(0);
    }

    // merge the two lh halves (lanes l and l^32 hold the same p)
    {
        float4 o;
        o.x = __shfl_xor(t.x, 32); o.y = __shfl_xor(t.y, 32);
        o.z = __shfl_xor(t.z, 32); o.w = __shfl_xor(t.w, 32);
        ins4(t, o.x); ins4(t, o.y); ins4(t, o.z); ins4(t, o.w);
        o.x = __shfl_xor(u.x, 32); o.y = __shfl_xor(u.y, 32);
        o.z = __shfl_xor(u.z, 32); o.w = __shfl_xor(u.w, 32);
        ins4(u, o.x); ins4(u, o.y); ins4(u, o.z); ins4(u, o.w);
    }
    if (lh == 0) {
        cells[(long)gw * CD + l31]      = t;   // p = l31
        cells[(long)gw * CD + l31 + 32] = u;   // p = l31+32
    }
}

// k2: 64 blocks x 1024 thr; block p: per-thread sorted top-4 over its rows
// of cells[.][p], then 16 rounds of block-wide min extraction. Last finished
// block (ticket) does the deterministic ordered final sum.
__global__ __launch_bounds__(1024) void k2_sel(
    const float4* __restrict__ cells, float* __restrict__ partial,
    unsigned* __restrict__ ticket, float* __restrict__ out)
{
    const int p = blockIdx.x;
    const int tid = threadIdx.x;
    const int lane = tid & 63, wid = tid >> 6;
    __shared__ unsigned long long wmin[16];

    float4 b0 = cells[(long)(tid)        * CD + p];
    float4 b1 = cells[(long)(tid + 1024) * CD + p];
    float4 b2 = cells[(long)(tid + 2048) * CD + p];
    float4 b3 = cells[(long)(tid + 3072) * CD + p];
    float4 b4 = (tid < K1_ROWS - 4096)
                ? cells[(long)(tid + 4096) * CD + p]
                : make_float4(FMAXV, FMAXV, FMAXV, FMAXV);

    float4 t = make_float4(FMAXV, FMAXV, FMAXV, FMAXV);
    ins4(t, b0.x); ins4(t, b0.y); ins4(t, b0.z); ins4(t, b0.w);
    ins4(t, b1.x); ins4(t, b1.y); ins4(t, b1.z); ins4(t, b1.w);
    ins4(t, b2.x); ins4(t, b2.y); ins4(t, b2.z); ins4(t, b2.w);
    ins4(t, b3.x); ins4(t, b3.y); ins4(t, b3.z); ins4(t, b3.w);
    ins4(t, b4.x); ins4(t, b4.y); ins4(t, b4.z); ins4(t, b4.w);

    float sum = 0.f;
    for (int rd = 0; rd < 16; ++rd) {
        unsigned long long key =
            ((unsigned long long)__float_as_uint(t.x) << 32) | (unsigned)tid;
#pragma unroll
        for (int off = 32; off; off >>= 1) {
            unsigned long long o = __shfl_xor(key, off);
            if (o < key) key = o;
        }
        if (lane == 0) wmin[wid] = key;
        __syncthreads();
        unsigned long long gk = wmin[0];
#pragma unroll
        for (int w = 1; w < 16; ++w) if (wmin[w] < gk) gk = wmin[w];
        sum += __uint_as_float((unsigned)(gk >> 32));
        if ((unsigned)(gk & 0xFFFFFFFFu) == (unsigned)tid) {
            t.x = t.y; t.y = t.z; t.z = t.w; t.w = FMAXV;   // pop local min
        }
        __syncthreads();
    }

    if (tid == 0) {
        partial[p] = sum;
        __threadfence();
        unsigned tk = atomicAdd(ticket, 1u);
        if (tk == CD - 1) {          // last block: deterministic ordered sum
            __threadfence();
            float s = 0.f;
            const volatile float* vp = partial;
            for (int q = 0; q < CD; ++q) s += vp[q];
            out[0] = -s / 1024.0f;
        }
    }
}

extern "C" void kernel_launch(void* const* d_in, const int* in_sizes, int n_in,
                              void* d_out, int out_size, void* d_ws, size_t ws_size,
                              hipStream_t stream)
{
    const float* f1   = (const float*)d_in[0];
    const float* f2   = (const float*)d_in[1];
    const int*   nidx = (const int*)d_in[3];     // negative_indices
    float* out = (float*)d_out;

    float4*   cells   = (float4*)d_ws;                          // 4608*64*16 = 4.7 MB
    short*    sel_bf  = (short*)(cells + (long)K1_ROWS * CD);   // 8 KB
    float*    sel2    = (float*)(sel_bf + CD * CD);
    float*    partial = sel2 + CD;
    unsigned* ticket  = (unsigned*)(partial + CD);

    kA_pack<<<CD,        64, 0, stream>>>(f1, nidx, sel_bf, sel2, ticket);
    k1_topk<<<K1_GRID,  256, 0, stream>>>(f2, sel_bf, sel2, cells);
    k2_sel <<<CD,      1024, 0, stream>>>(cells, partial, ticket, out);
}